// Round 1
// baseline (149.423 us; speedup 1.0000x reference)
//
#include <hip/hip_runtime.h>

// EmbedLinear: out[b, :F] = in[b, :]; out[b, F+c] = in[b, parents[c]] * values[c]
// B=16384, F=4096, C=4096, fp32. Pure memory-bound: 256 MiB read + 512 MiB write.
// One block per row; row staged in LDS (16 KiB) so the 4096-way column gather
// never touches HBM. parents/values re-read per block but L2-resident.

constexpr int F = 4096;
constexpr int C = 4096;
constexpr int OUTW = F + C;
constexpr int BLOCK = 256;

__global__ __launch_bounds__(BLOCK) void embed_linear_kernel(
    const float* __restrict__ in,
    const float* __restrict__ values,
    const int*   __restrict__ parents,
    float*       __restrict__ out)
{
    __shared__ float row[F];

    const int b = blockIdx.x;
    const int t = threadIdx.x;

    const float4* in4  = reinterpret_cast<const float4*>(in + (size_t)b * F);
    float4*       out4 = reinterpret_cast<float4*>(out + (size_t)b * OUTW);
    float4*       row4 = reinterpret_cast<float4*>(row);

    // Phase 1: copy row -> out[:, :F] and stage in LDS. 1024 float4s / 256 thr = 4 each.
    #pragma unroll
    for (int i = 0; i < F / 4 / BLOCK; ++i) {
        int idx = i * BLOCK + t;
        float4 v = in4[idx];
        out4[idx] = v;
        row4[idx] = v;
    }
    __syncthreads();

    // Phase 2: gather-scale. 1024 (int4,float4) pairs / 256 thr = 4 each.
    const int4*   par4 = reinterpret_cast<const int4*>(parents);
    const float4* val4 = reinterpret_cast<const float4*>(values);
    float4*       og4  = reinterpret_cast<float4*>(out + (size_t)b * OUTW + F);

    #pragma unroll
    for (int i = 0; i < C / 4 / BLOCK; ++i) {
        int idx = i * BLOCK + t;
        int4   p = par4[idx];
        float4 v = val4[idx];
        float4 r;
        r.x = row[p.x] * v.x;
        r.y = row[p.y] * v.y;
        r.z = row[p.z] * v.z;
        r.w = row[p.w] * v.w;
        og4[idx] = r;
    }
}

extern "C" void kernel_launch(void* const* d_in, const int* in_sizes, int n_in,
                              void* d_out, int out_size, void* d_ws, size_t ws_size,
                              hipStream_t stream) {
    const float* in      = (const float*)d_in[0];
    const float* values  = (const float*)d_in[1];
    const int*   parents = (const int*)d_in[2];
    float*       out     = (float*)d_out;

    const int B = in_sizes[0] / F;  // 16384
    embed_linear_kernel<<<B, BLOCK, 0, stream>>>(in, values, parents, out);
}

// Round 2
// 118.545 us; speedup vs baseline: 1.2605x; 1.2605x over previous
//
#include <hip/hip_runtime.h>

// EmbedLinear: out[b, :F] = in[b, :]; out[b, F+c] = in[b, parents[c]] * values[c]
// B=16384, F=4096, C=4096, fp32. Memory-bound: 256 MiB read + 512 MiB write,
// floor ~128 us at 6.3 TB/s.
//
// R2 changes vs R1 (149.4 us):
//  - No global store before __syncthreads (barrier forces vmcnt(0) drain;
//    R1 paid a store-ack stall per block for nothing).
//  - Nontemporal stores for the 512 MiB write-once output stream (don't
//    evict L2-hot parents/values or fight the input read stream).
//  - parents/values prefetched to registers before the barrier.

constexpr int F = 4096;
constexpr int C = 4096;
constexpr int OUTW = F + C;
constexpr int BLOCK = 256;
constexpr int ITER = F / 4 / BLOCK;  // 4

typedef float  vf4 __attribute__((ext_vector_type(4)));
typedef int    vi4 __attribute__((ext_vector_type(4)));

__global__ __launch_bounds__(BLOCK) void embed_linear_kernel(
    const float* __restrict__ in,
    const float* __restrict__ values,
    const int*   __restrict__ parents,
    float*       __restrict__ out)
{
    __shared__ float row[F];

    const int b = blockIdx.x;
    const int t = threadIdx.x;

    const vf4* in4  = reinterpret_cast<const vf4*>(in + (size_t)b * F);
    const vi4* par4 = reinterpret_cast<const vi4*>(parents);
    const vf4* val4 = reinterpret_cast<const vf4*>(values);
    vf4*       row4 = reinterpret_cast<vf4*>(row);
    vf4*       out4 = reinterpret_cast<vf4*>(out + (size_t)b * OUTW);
    vf4*       og4  = reinterpret_cast<vf4*>(out + (size_t)b * OUTW + F);

    // Load row + parents/values into registers (all loads in flight together).
    vf4 v[ITER];
    vi4 p[ITER];
    vf4 w[ITER];
    #pragma unroll
    for (int i = 0; i < ITER; ++i) v[i] = in4[i * BLOCK + t];
    #pragma unroll
    for (int i = 0; i < ITER; ++i) {
        p[i] = par4[i * BLOCK + t];
        w[i] = val4[i * BLOCK + t];
    }

    // Stage row in LDS; barrier waits on LDS + loads only (no stores issued yet).
    #pragma unroll
    for (int i = 0; i < ITER; ++i) row4[i * BLOCK + t] = v[i];
    __syncthreads();

    // Copy-through half (nontemporal: write-once stream).
    #pragma unroll
    for (int i = 0; i < ITER; ++i)
        __builtin_nontemporal_store(v[i], &out4[i * BLOCK + t]);

    // Gather-scale half.
    #pragma unroll
    for (int i = 0; i < ITER; ++i) {
        vf4 r;
        r.x = row[p[i].x] * w[i].x;
        r.y = row[p[i].y] * w[i].y;
        r.z = row[p[i].z] * w[i].z;
        r.w = row[p[i].w] * w[i].w;
        __builtin_nontemporal_store(r, &og4[i * BLOCK + t]);
    }
}

extern "C" void kernel_launch(void* const* d_in, const int* in_sizes, int n_in,
                              void* d_out, int out_size, void* d_ws, size_t ws_size,
                              hipStream_t stream) {
    const float* in      = (const float*)d_in[0];
    const float* values  = (const float*)d_in[1];
    const int*   parents = (const int*)d_in[2];
    float*       out     = (float*)d_out;

    const int B = in_sizes[0] / F;  // 16384
    embed_linear_kernel<<<B, BLOCK, 0, stream>>>(in, values, parents, out);
}